// Round 9
// baseline (1055.797 us; speedup 1.0000x reference)
//
#include <hip/hip_runtime.h>
#include <hip/hip_fp16.h>

// out[e] = edge_attr[e] / segsum(edge_attr, row)[col[e]]
//
// Per-XCD-replica atomic reduction (replaces the whole counting-sort pipeline):
//   Device-scope f32 atomics execute memory-side (round 1: 30B write-through
//   per atomic, 609MB, 925us). WORKGROUP-scope atomics execute in the issuing
//   XCD's local L2 (no sc1 memory-side bypass). Each XCD gets a private 4MB
//   rowsum replica (selected via s_getreg HW_REG_XCC_ID, verified 0..7 on
//   MI355X), so all atomics to a replica come from one XCD's L2 -> coherent
//   physically; end-of-kernel cache flush publishes them for the merge.
//   P1 zero:   zero the 8 replicas (32 MB).
//   P2 scatter: nt-stream edges, 4 workgroup-scope atomicAdds/iter into
//               replica[xcc]. Fire-and-forget -> no latency chain.
//   P3 merge:  rnorm16[i] = (f16) 1/sum_x rep[x][i]   (2 MB table).
//   P4 gather: out[e] = rnorm16[col[e]] * attr[e]  (round-6 proven form).
// Fallback (ws too small): round-0 device-atomic version.

typedef int      v4i __attribute__((ext_vector_type(4)));
typedef float    v4f __attribute__((ext_vector_type(4)));

#define NR   (1 << 20)     // replica stride in nodes; supports N <= 1,048,576
#define NXCD 8

__device__ __forceinline__ int xcc_id() {
    int x;
    asm volatile("s_getreg_b32 %0, hwreg(HW_REG_XCC_ID)" : "=s"(x));
    return x & (NXCD - 1);
}

// ---------------- fast path ----------------

__global__ __launch_bounds__(256) void zero_reps_kernel(float* __restrict__ reps) {
    const int total4 = (NXCD * NR) >> 2;
    const int stride = gridDim.x * blockDim.x;
    const v4f z = {0.0f, 0.0f, 0.0f, 0.0f};
    for (int i = blockIdx.x * blockDim.x + threadIdx.x; i < total4; i += stride)
        reinterpret_cast<v4f*>(reps)[i] = z;
}

__global__ __launch_bounds__(256) void scatter_xcd_kernel(
    const int* __restrict__ row, const float* __restrict__ attr,
    float* __restrict__ reps, int E)
{
    float* rep = reps + (size_t)xcc_id() * NR;   // wave-uniform, block on one XCD
    const int tid = blockIdx.x * blockDim.x + threadIdx.x;
    const int stride = gridDim.x * blockDim.x;
    const int E4 = E >> 2;
    for (int i = tid; i < E4; i += stride) {
        const v4i r = __builtin_nontemporal_load(reinterpret_cast<const v4i*>(row) + i);
        const v4f a = __builtin_nontemporal_load(reinterpret_cast<const v4f*>(attr) + i);
        __hip_atomic_fetch_add(&rep[r.x], a.x, __ATOMIC_RELAXED, __HIP_MEMORY_SCOPE_WORKGROUP);
        __hip_atomic_fetch_add(&rep[r.y], a.y, __ATOMIC_RELAXED, __HIP_MEMORY_SCOPE_WORKGROUP);
        __hip_atomic_fetch_add(&rep[r.z], a.z, __ATOMIC_RELAXED, __HIP_MEMORY_SCOPE_WORKGROUP);
        __hip_atomic_fetch_add(&rep[r.w], a.w, __ATOMIC_RELAXED, __HIP_MEMORY_SCOPE_WORKGROUP);
    }
    for (int e = (E4 << 2) + tid; e < E; e += stride)
        __hip_atomic_fetch_add(&rep[row[e]], attr[e], __ATOMIC_RELAXED, __HIP_MEMORY_SCOPE_WORKGROUP);
}

__global__ __launch_bounds__(256) void merge_recip_kernel(
    const float* __restrict__ reps, __half* __restrict__ rnorm16,
    const int* __restrict__ Np)
{
    const int N = *Np;
    const int stride = gridDim.x * blockDim.x;
    for (int i = blockIdx.x * blockDim.x + threadIdx.x; i < N; i += stride) {
        float s = 0.0f;
        #pragma unroll
        for (int x = 0; x < NXCD; ++x) s += reps[(size_t)x * NR + i];
        rnorm16[i] = __float2half(1.0f / s);
    }
}

// gather: round-6 proven 4x-unrolled grid-stride form (~115us)
__global__ __launch_bounds__(256) void gather_scale_f16_kernel(
    const int* __restrict__ col, const float* __restrict__ attr,
    const __half* __restrict__ rn, float* __restrict__ out, int E)
{
    const int tid = blockIdx.x * blockDim.x + threadIdx.x;
    const int stride = gridDim.x * blockDim.x;
    const int E4 = E >> 2;
    const v4i* col4  = reinterpret_cast<const v4i*>(col);
    const v4f* attr4 = reinterpret_cast<const v4f*>(attr);
    v4f*       out4  = reinterpret_cast<v4f*>(out);

    int i = tid;
    for (; i + 3 * stride < E4; i += 4 * stride) {       // 16 random loads in flight
        const v4i c0 = __builtin_nontemporal_load(col4 + i);
        const v4i c1 = __builtin_nontemporal_load(col4 + i + stride);
        const v4i c2 = __builtin_nontemporal_load(col4 + i + 2 * stride);
        const v4i c3 = __builtin_nontemporal_load(col4 + i + 3 * stride);
        const v4f a0 = __builtin_nontemporal_load(attr4 + i);
        const v4f a1 = __builtin_nontemporal_load(attr4 + i + stride);
        const v4f a2 = __builtin_nontemporal_load(attr4 + i + 2 * stride);
        const v4f a3 = __builtin_nontemporal_load(attr4 + i + 3 * stride);
        v4f o0, o1, o2, o3;
        o0.x = __half2float(rn[c0.x]) * a0.x; o0.y = __half2float(rn[c0.y]) * a0.y;
        o0.z = __half2float(rn[c0.z]) * a0.z; o0.w = __half2float(rn[c0.w]) * a0.w;
        o1.x = __half2float(rn[c1.x]) * a1.x; o1.y = __half2float(rn[c1.y]) * a1.y;
        o1.z = __half2float(rn[c1.z]) * a1.z; o1.w = __half2float(rn[c1.w]) * a1.w;
        o2.x = __half2float(rn[c2.x]) * a2.x; o2.y = __half2float(rn[c2.y]) * a2.y;
        o2.z = __half2float(rn[c2.z]) * a2.z; o2.w = __half2float(rn[c2.w]) * a2.w;
        o3.x = __half2float(rn[c3.x]) * a3.x; o3.y = __half2float(rn[c3.y]) * a3.y;
        o3.z = __half2float(rn[c3.z]) * a3.z; o3.w = __half2float(rn[c3.w]) * a3.w;
        __builtin_nontemporal_store(o0, out4 + i);
        __builtin_nontemporal_store(o1, out4 + i + stride);
        __builtin_nontemporal_store(o2, out4 + i + 2 * stride);
        __builtin_nontemporal_store(o3, out4 + i + 3 * stride);
    }
    for (; i < E4; i += stride) {
        const v4i c = __builtin_nontemporal_load(col4 + i);
        const v4f a = __builtin_nontemporal_load(attr4 + i);
        v4f o;
        o.x = __half2float(rn[c.x]) * a.x; o.y = __half2float(rn[c.y]) * a.y;
        o.z = __half2float(rn[c.z]) * a.z; o.w = __half2float(rn[c.w]) * a.w;
        __builtin_nontemporal_store(o, out4 + i);
    }
    for (int e = (E4 << 2) + tid; e < E; e += stride)
        out[e] = __half2float(rn[col[e]]) * attr[e];
}

// ---------------- fallback path (device-scope atomics, f32) ----------------

__global__ void zero_ws_kernel(float* __restrict__ ws, const int* __restrict__ Np) {
    const int N = *Np;
    const int stride = gridDim.x * blockDim.x;
    for (int i = blockIdx.x * blockDim.x + threadIdx.x; i < N; i += stride)
        ws[i] = 0.0f;
}

__global__ void rowsum_atomic_kernel(const int* __restrict__ row,
                                     const float* __restrict__ attr,
                                     float* __restrict__ rowsum, int E) {
    const int tid = blockIdx.x * blockDim.x + threadIdx.x;
    const int stride = gridDim.x * blockDim.x;
    const int E4 = E >> 2;
    for (int i = tid; i < E4; i += stride) {
        const int4   r = reinterpret_cast<const int4*>(row)[i];
        const float4 a = reinterpret_cast<const float4*>(attr)[i];
        atomicAdd(&rowsum[r.x], a.x);
        atomicAdd(&rowsum[r.y], a.y);
        atomicAdd(&rowsum[r.z], a.z);
        atomicAdd(&rowsum[r.w], a.w);
    }
    for (int i = (E4 << 2) + tid; i < E; i += stride)
        atomicAdd(&rowsum[row[i]], attr[i]);
}

__global__ void recip_fallback_kernel(float* __restrict__ rowsum,
                                      const int* __restrict__ Np) {
    const int N = *Np;
    const int stride = gridDim.x * blockDim.x;
    for (int i = blockIdx.x * blockDim.x + threadIdx.x; i < N; i += stride)
        rowsum[i] = 1.0f / rowsum[i];
}

__global__ __launch_bounds__(256) void gather_scale_f32_kernel(
    const int* __restrict__ col, const float* __restrict__ attr,
    const float* __restrict__ rnorm, float* __restrict__ out, int E)
{
    const int tid = blockIdx.x * blockDim.x + threadIdx.x;
    const int stride = gridDim.x * blockDim.x;
    const int E4 = E >> 2;
    const v4i* col4  = reinterpret_cast<const v4i*>(col);
    const v4f* attr4 = reinterpret_cast<const v4f*>(attr);
    v4f*       out4  = reinterpret_cast<v4f*>(out);
    for (int i = tid; i < E4; i += stride) {
        const v4i c = __builtin_nontemporal_load(col4 + i);
        const v4f a = __builtin_nontemporal_load(attr4 + i);
        v4f o;
        o.x = rnorm[c.x] * a.x; o.y = rnorm[c.y] * a.y;
        o.z = rnorm[c.z] * a.z; o.w = rnorm[c.w] * a.w;
        __builtin_nontemporal_store(o, out4 + i);
    }
    for (int e = (E4 << 2) + tid; e < E; e += stride)
        out[e] = rnorm[col[e]] * attr[e];
}

// ---------------- launch ----------------

extern "C" void kernel_launch(void* const* d_in, const int* in_sizes, int n_in,
                              void* d_out, int out_size, void* d_ws, size_t ws_size,
                              hipStream_t stream) {
    const int*   edge_index = (const int*)d_in[0];     // [2, E]
    const float* edge_attr  = (const float*)d_in[1];   // [E]
    const int*   Np         = (const int*)d_in[2];     // scalar N (device)

    const int E = in_sizes[1];
    const int* row = edge_index;
    const int* col = edge_index + E;
    float* out = (float*)d_out;

    auto align256 = [](size_t x) { return (x + 255) & ~(size_t)255; };
    const size_t rn16Bytes = align256((size_t)NR * sizeof(__half));        // 2 MB
    const size_t repsBytes = (size_t)NXCD * NR * sizeof(float);            // 32 MB
    const size_t need = rn16Bytes + repsBytes;

    if (ws_size >= need) {
        __half* rnorm16 = (__half*)d_ws;
        float*  reps    = (float*)((char*)d_ws + rn16Bytes);

        zero_reps_kernel      <<<2048, 256, 0, stream>>>(reps);
        scatter_xcd_kernel    <<<2048, 256, 0, stream>>>(row, edge_attr, reps, E);
        merge_recip_kernel    <<<2048, 256, 0, stream>>>(reps, rnorm16, Np);
        gather_scale_f16_kernel<<<2048, 256, 0, stream>>>(col, edge_attr, rnorm16, out, E);
    } else {
        float* rowsum = (float*)d_ws;
        const int workE = (E + 3) >> 2;
        int gE = (workE + 255) / 256;
        if (gE > 2048) gE = 2048;
        zero_ws_kernel         <<<2048, 256, 0, stream>>>(rowsum, Np);
        rowsum_atomic_kernel   <<<gE, 256, 0, stream>>>(row, edge_attr, rowsum, E);
        recip_fallback_kernel  <<<2048, 256, 0, stream>>>(rowsum, Np);
        gather_scale_f32_kernel<<<2048, 256, 0, stream>>>(col, edge_attr, rowsum, out, E);
    }
}

// Round 10
// 339.791 us; speedup vs baseline: 3.1072x; 3.1072x over previous
//
#include <hip/hip_runtime.h>
#include <hip/hip_fp16.h>
#include <stdint.h>

// out[e] = edge_attr[e] / segsum(edge_attr, row)[col[e]]
//
// Counting-sort by 8192-wide node bucket, exact atomic-free scatter offsets.
// Round-10 change: nt hints ONLY on truly-dead streams (col/attr reads in
// gather, out stores). All produce-then-consume traffic (row for hist->scatter,
// pairs for scatter->reduce, partials) uses REGULAR loads/stores so the 256MB
// L3 can absorb it (rounds 1-9 ran every pass at ~2 TB/s because nt stores
// forced 160MB of pairs to HBM and nt loads kept row from being L3-cached).
//   P1 hist:    per-tile bucket histogram -> histG[tile][b]
//   P2 totals:  totals[b] = sum_t histG[t][b]
//   P3 bases:   exclusive scan of even-rounded totals -> bases[b]
//   P4 offsets: per-bucket exclusive scan over tiles -> offG[t][b]
//   P5 scatter: regs-resident tile, LDS-atomic rank, wave0 shfl scan,
//               LDS stage, coalesced flush at exact offsets
//   P6 reduce:  nSplit blocks/bucket stream pairs, LDS f32 bins -> partials
//   P7 recip:   rnorm16[i] = (f16) 1/sum_q partial[q][i]   (2 MB table)
//   P8 gather:  out[e] = rnorm16[col[e]] * attr[e], 4x unroll
// Fallback (small ws): direct-atomic version.

typedef int      v4i __attribute__((ext_vector_type(4)));
typedef float    v4f __attribute__((ext_vector_type(4)));
typedef unsigned v4u __attribute__((ext_vector_type(4)));
using ull = unsigned long long;

#define BKT_BITS 13
#define BKT_W    (1 << BKT_BITS)      // 8192 nodes per bucket
#define NB       128                   // supports N <= 1,048,576
#define NMAX     (NB << BKT_BITS)
#define TILE     4096
#define BLOCK1   512
#define BLOCK2   1024

// ---------------- fast path ----------------

__global__ __launch_bounds__(BLOCK1) void hist_kernel(
    const int* __restrict__ row, int* __restrict__ histG, int E)
{
    __shared__ int h[NB];
    const int t = threadIdx.x;
    const long base = (long)blockIdx.x * TILE;
    if (t < NB) h[t] = 0;
    __syncthreads();
    if (base + TILE <= (long)E) {
        #pragma unroll
        for (int k = 0; k < 2; ++k) {
            const long e0 = base + ((long)(k * BLOCK1 + t) << 2);
            const v4i rv = *reinterpret_cast<const v4i*>(row + e0);  // regular: row -> L3 for scatter
            atomicAdd(&h[rv.x >> BKT_BITS], 1);
            atomicAdd(&h[rv.y >> BKT_BITS], 1);
            atomicAdd(&h[rv.z >> BKT_BITS], 1);
            atomicAdd(&h[rv.w >> BKT_BITS], 1);
        }
    } else {
        for (int k = 0; k < 2; ++k) {
            const long e0 = base + ((long)(k * BLOCK1 + t) << 2);
            for (int j = 0; j < 4; ++j)
                if (e0 + j < (long)E) atomicAdd(&h[row[e0 + j] >> BKT_BITS], 1);
        }
    }
    __syncthreads();
    if (t < NB) histG[(size_t)blockIdx.x * NB + t] = h[t];
}

__global__ __launch_bounds__(256) void totals_kernel(
    const int* __restrict__ histG, int* __restrict__ totals, int nTiles)
{
    __shared__ int s[256];
    const int b = blockIdx.x;
    int acc = 0;
    for (int t = threadIdx.x; t < nTiles; t += 256)
        acc += histG[(size_t)t * NB + b];
    s[threadIdx.x] = acc;
    __syncthreads();
    for (int o = 128; o > 0; o >>= 1) {
        if (threadIdx.x < o) s[threadIdx.x] += s[threadIdx.x + o];
        __syncthreads();
    }
    if (threadIdx.x == 0) totals[b] = s[0];
}

__global__ __launch_bounds__(NB) void bases_kernel(
    const int* __restrict__ totals, int* __restrict__ bases)
{
    __shared__ int s[NB];
    const int t = threadIdx.x;
    const int rc = (totals[t] + 1) & ~1;      // even-rounded -> 16B-aligned regions
    s[t] = rc;
    __syncthreads();
    for (int off = 1; off < NB; off <<= 1) {
        const int v = (t >= off) ? s[t - off] : 0;
        __syncthreads();
        s[t] += v;
        __syncthreads();
    }
    bases[t] = s[t] - rc;
}

__global__ __launch_bounds__(256) void offsets_kernel(
    const int* __restrict__ histG, const int* __restrict__ bases,
    int* __restrict__ offG, int nTiles)
{
    __shared__ int s[256];
    const int b = blockIdx.x;
    const int seg = (nTiles + 255) >> 8;
    const int t0 = threadIdx.x * seg;
    int acc = 0;
    for (int k = 0; k < seg; ++k) {
        const int t = t0 + k;
        if (t < nTiles) acc += histG[(size_t)t * NB + b];
    }
    s[threadIdx.x] = acc;
    __syncthreads();
    for (int off = 1; off < 256; off <<= 1) {
        const int v = (threadIdx.x >= off) ? s[threadIdx.x - off] : 0;
        __syncthreads();
        s[threadIdx.x] += v;
        __syncthreads();
    }
    int run = bases[b] + s[threadIdx.x] - acc;     // exclusive base for my segment
    for (int k = 0; k < seg; ++k) {
        const int t = t0 + k;
        if (t < nTiles) {
            offG[(size_t)t * NB + b] = run;
            run += histG[(size_t)t * NB + b];
        }
    }
}

__global__ __launch_bounds__(BLOCK1) void scatter_kernel(
    const int* __restrict__ row, const float* __restrict__ attr,
    const int* __restrict__ offG, ull* __restrict__ pairsG, int E)
{
    __shared__ int cnt[NB];
    __shared__ int scanb[NB];
    __shared__ int gbase[NB];
    __shared__ ull pairs[TILE];                    // 32 KB

    const int  t    = threadIdx.x;
    const long base = (long)blockIdx.x * TILE;
    const bool full = (base + TILE <= (long)E);

    if (t < NB) cnt[t] = 0;
    __syncthreads();

    int r[8]; float a[8]; int rk[8];
    if (full) {
        #pragma unroll
        for (int k = 0; k < 2; ++k) {
            const long e0 = base + ((long)(k * BLOCK1 + t) << 2);
            const v4i rv = *reinterpret_cast<const v4i*>(row + e0);   // L3-hot from hist
            const v4f av = __builtin_nontemporal_load(reinterpret_cast<const v4f*>(attr + e0));
            r[k*4+0]=rv.x; r[k*4+1]=rv.y; r[k*4+2]=rv.z; r[k*4+3]=rv.w;
            a[k*4+0]=av.x; a[k*4+1]=av.y; a[k*4+2]=av.z; a[k*4+3]=av.w;
        }
        #pragma unroll
        for (int i = 0; i < 8; ++i)
            rk[i] = atomicAdd(&cnt[r[i] >> BKT_BITS], 1);
    } else {
        for (int k = 0; k < 2; ++k) {
            const long e0 = base + ((long)(k * BLOCK1 + t) << 2);
            for (int j = 0; j < 4; ++j) {
                const int i = k*4 + j;
                if (e0 + j < (long)E) {
                    r[i] = row[e0 + j]; a[i] = attr[e0 + j];
                    rk[i] = atomicAdd(&cnt[r[i] >> BKT_BITS], 1);
                } else r[i] = -1;
            }
        }
    }
    __syncthreads();

    // wave-0 exclusive scan of the 128 bucket counts (2 bins/lane)
    if (t < 64) {
        const int h0 = cnt[2*t], h1 = cnt[2*t+1];
        const int sum = h0 + h1;
        int x = sum;
        #pragma unroll
        for (int off = 1; off < 64; off <<= 1) {
            const int y = __shfl_up(x, off);
            if (t >= off) x += y;
        }
        const int excl = x - sum;
        scanb[2*t]   = excl;
        scanb[2*t+1] = excl + h0;
    }
    if (t < NB) gbase[t] = offG[(size_t)blockIdx.x * NB + t];   // exact, no atomic
    __syncthreads();

    #pragma unroll
    for (int i = 0; i < 8; ++i)
        if (r[i] >= 0)
            pairs[scanb[r[i] >> BKT_BITS] + rk[i]] =
                ((ull)__float_as_uint(a[i]) << 32) | (unsigned)r[i];
    __syncthreads();

    const int total = full ? TILE : (int)((long)E - base);
    for (int s = t; s < total; s += BLOCK1) {
        const ull p  = pairs[s];
        const int bb = (int)(((unsigned)p) >> BKT_BITS);
        const size_t dst = (size_t)gbase[bb] + (size_t)(s - scanb[bb]);
        pairsG[dst] = p;                           // REGULAR store -> L2/L3 keeps it for reduce
    }
}

__global__ __launch_bounds__(BLOCK2) void reduce_kernel(
    const ull* __restrict__ pairsG, const int* __restrict__ totals,
    const int* __restrict__ bases, float* __restrict__ partial, int nSplit)
{
    __shared__ float bins[BKT_W];                  // 32 KB
    const int b = blockIdx.x / nSplit;
    const int q = blockIdx.x % nSplit;
    for (int i = threadIdx.x; i < BKT_W; i += BLOCK2) bins[i] = 0.0f;
    __syncthreads();

    const int cnt = totals[b];
    const ull* src = pairsG + (size_t)bases[b];    // even base -> 16B aligned
    const int Q = cnt >> 2;
    for (int i = q * BLOCK2 + threadIdx.x; i < Q; i += nSplit * BLOCK2) {
        const v4u p0 = *reinterpret_cast<const v4u*>(src + 4*(size_t)i);      // L3-hot
        const v4u p1 = *reinterpret_cast<const v4u*>(src + 4*(size_t)i + 2);
        atomicAdd(&bins[p0.x & (BKT_W-1)], __uint_as_float(p0.y));
        atomicAdd(&bins[p0.z & (BKT_W-1)], __uint_as_float(p0.w));
        atomicAdd(&bins[p1.x & (BKT_W-1)], __uint_as_float(p1.y));
        atomicAdd(&bins[p1.z & (BKT_W-1)], __uint_as_float(p1.w));
    }
    const int rem = cnt - (Q << 2);
    if (q == 0 && threadIdx.x < rem) {
        const ull p = src[(Q << 2) + threadIdx.x];
        atomicAdd(&bins[(unsigned)p & (BKT_W-1)], __uint_as_float((unsigned)(p >> 32)));
    }
    __syncthreads();

    float* dst = partial + (size_t)q * NMAX + ((size_t)b << BKT_BITS);
    for (int i = threadIdx.x; i < BKT_W; i += BLOCK2)
        dst[i] = bins[i];                          // regular: partials read by recip
}

__global__ void recip_kernel(const float* __restrict__ partial,
                             __half* __restrict__ rnorm16,
                             const int* __restrict__ Np, int nSplit) {
    const int N = *Np;
    const int stride = gridDim.x * blockDim.x;
    for (int i = blockIdx.x * blockDim.x + threadIdx.x; i < N; i += stride) {
        float s = 0.0f;
        for (int q = 0; q < nSplit; ++q) s += partial[(size_t)q * NMAX + i];
        rnorm16[i] = __float2half(1.0f / s);
    }
}

// ---------------- gather pass (f16 table, 4x unroll) ----------------

__global__ __launch_bounds__(256) void gather_scale_f16_kernel(
    const int* __restrict__ col, const float* __restrict__ attr,
    const __half* __restrict__ rn, float* __restrict__ out, int E)
{
    const int tid = blockIdx.x * blockDim.x + threadIdx.x;
    const int stride = gridDim.x * blockDim.x;
    const int E4 = E >> 2;
    const v4i* col4  = reinterpret_cast<const v4i*>(col);
    const v4f* attr4 = reinterpret_cast<const v4f*>(attr);
    v4f*       out4  = reinterpret_cast<v4f*>(out);

    int i = tid;
    for (; i + 3 * stride < E4; i += 4 * stride) {       // 16 random loads in flight
        const v4i c0 = __builtin_nontemporal_load(col4 + i);
        const v4i c1 = __builtin_nontemporal_load(col4 + i + stride);
        const v4i c2 = __builtin_nontemporal_load(col4 + i + 2 * stride);
        const v4i c3 = __builtin_nontemporal_load(col4 + i + 3 * stride);
        const v4f a0 = __builtin_nontemporal_load(attr4 + i);
        const v4f a1 = __builtin_nontemporal_load(attr4 + i + stride);
        const v4f a2 = __builtin_nontemporal_load(attr4 + i + 2 * stride);
        const v4f a3 = __builtin_nontemporal_load(attr4 + i + 3 * stride);
        v4f o0, o1, o2, o3;
        o0.x = __half2float(rn[c0.x]) * a0.x; o0.y = __half2float(rn[c0.y]) * a0.y;
        o0.z = __half2float(rn[c0.z]) * a0.z; o0.w = __half2float(rn[c0.w]) * a0.w;
        o1.x = __half2float(rn[c1.x]) * a1.x; o1.y = __half2float(rn[c1.y]) * a1.y;
        o1.z = __half2float(rn[c1.z]) * a1.z; o1.w = __half2float(rn[c1.w]) * a1.w;
        o2.x = __half2float(rn[c2.x]) * a2.x; o2.y = __half2float(rn[c2.y]) * a2.y;
        o2.z = __half2float(rn[c2.z]) * a2.z; o2.w = __half2float(rn[c2.w]) * a2.w;
        o3.x = __half2float(rn[c3.x]) * a3.x; o3.y = __half2float(rn[c3.y]) * a3.y;
        o3.z = __half2float(rn[c3.z]) * a3.z; o3.w = __half2float(rn[c3.w]) * a3.w;
        __builtin_nontemporal_store(o0, out4 + i);
        __builtin_nontemporal_store(o1, out4 + i + stride);
        __builtin_nontemporal_store(o2, out4 + i + 2 * stride);
        __builtin_nontemporal_store(o3, out4 + i + 3 * stride);
    }
    for (; i < E4; i += stride) {
        const v4i c = __builtin_nontemporal_load(col4 + i);
        const v4f a = __builtin_nontemporal_load(attr4 + i);
        v4f o;
        o.x = __half2float(rn[c.x]) * a.x; o.y = __half2float(rn[c.y]) * a.y;
        o.z = __half2float(rn[c.z]) * a.z; o.w = __half2float(rn[c.w]) * a.w;
        __builtin_nontemporal_store(o, out4 + i);
    }
    for (int e = (E4 << 2) + tid; e < E; e += stride)
        out[e] = __half2float(rn[col[e]]) * attr[e];
}

// ---------------- fallback path (f32, direct atomics) ----------------

__global__ void zero_ws_kernel(float* __restrict__ ws, const int* __restrict__ Np) {
    const int N = *Np;
    const int stride = gridDim.x * blockDim.x;
    for (int i = blockIdx.x * blockDim.x + threadIdx.x; i < N; i += stride)
        ws[i] = 0.0f;
}

__global__ void rowsum_atomic_kernel(const int* __restrict__ row,
                                     const float* __restrict__ attr,
                                     float* __restrict__ rowsum, int E) {
    const int tid = blockIdx.x * blockDim.x + threadIdx.x;
    const int stride = gridDim.x * blockDim.x;
    const int E4 = E >> 2;
    for (int i = tid; i < E4; i += stride) {
        const int4   r = reinterpret_cast<const int4*>(row)[i];
        const float4 a = reinterpret_cast<const float4*>(attr)[i];
        atomicAdd(&rowsum[r.x], a.x);
        atomicAdd(&rowsum[r.y], a.y);
        atomicAdd(&rowsum[r.z], a.z);
        atomicAdd(&rowsum[r.w], a.w);
    }
    for (int i = (E4 << 2) + tid; i < E; i += stride)
        atomicAdd(&rowsum[row[i]], attr[i]);
}

__global__ void recip_fallback_kernel(float* __restrict__ rowsum,
                                      const int* __restrict__ Np) {
    const int N = *Np;
    const int stride = gridDim.x * blockDim.x;
    for (int i = blockIdx.x * blockDim.x + threadIdx.x; i < N; i += stride)
        rowsum[i] = 1.0f / rowsum[i];
}

__global__ __launch_bounds__(256) void gather_scale_f32_kernel(
    const int* __restrict__ col, const float* __restrict__ attr,
    const float* __restrict__ rnorm, float* __restrict__ out, int E)
{
    const int tid = blockIdx.x * blockDim.x + threadIdx.x;
    const int stride = gridDim.x * blockDim.x;
    const int E4 = E >> 2;
    const v4i* col4  = reinterpret_cast<const v4i*>(col);
    const v4f* attr4 = reinterpret_cast<const v4f*>(attr);
    v4f*       out4  = reinterpret_cast<v4f*>(out);
    for (int i = tid; i < E4; i += stride) {
        const v4i c = __builtin_nontemporal_load(col4 + i);
        const v4f a = __builtin_nontemporal_load(attr4 + i);
        v4f o;
        o.x = rnorm[c.x] * a.x; o.y = rnorm[c.y] * a.y;
        o.z = rnorm[c.z] * a.z; o.w = rnorm[c.w] * a.w;
        __builtin_nontemporal_store(o, out4 + i);
    }
    for (int e = (E4 << 2) + tid; e < E; e += stride)
        out[e] = rnorm[col[e]] * attr[e];
}

// ---------------- launch ----------------

extern "C" void kernel_launch(void* const* d_in, const int* in_sizes, int n_in,
                              void* d_out, int out_size, void* d_ws, size_t ws_size,
                              hipStream_t stream) {
    const int*   edge_index = (const int*)d_in[0];     // [2, E]
    const float* edge_attr  = (const float*)d_in[1];   // [E]
    const int*   Np         = (const int*)d_in[2];     // scalar N (device)

    const int E = in_sizes[1];
    const int* row = edge_index;
    const int* col = edge_index + E;
    float* out = (float*)d_out;

    const int nTiles = (E + TILE - 1) / TILE;
    auto align256 = [](size_t x) { return (x + 255) & ~(size_t)255; };

    size_t off = 0;
    const size_t basesOff  = off; off += align256(NB * sizeof(int));
    const size_t totalsOff = off; off += align256(NB * sizeof(int));
    const size_t rn16Off   = off; off += align256((size_t)NMAX * sizeof(__half)); // 2 MB
    const size_t partOff   = off;
    const size_t histBytes = align256((size_t)nTiles * NB * sizeof(int));
    const size_t scanBytes = 2 * histBytes;                    // histG + offG
    const size_t pairsBytes = ((size_t)E + 2 * NB) * sizeof(ull);

    int nSplit = 0;
    size_t partRegion = 0;
    for (int c : {8, 4, 2, 1}) {
        size_t pr = (size_t)c * NMAX * sizeof(float);
        if (pr < scanBytes) pr = scanBytes;
        if (partOff + pr + pairsBytes <= ws_size) { nSplit = c; partRegion = pr; break; }
    }

    if (nSplit > 0) {
        int*    bases   = (int*)   ((char*)d_ws + basesOff);
        int*    totals  = (int*)   ((char*)d_ws + totalsOff);
        __half* rnorm16 = (__half*)((char*)d_ws + rn16Off);
        float*  partial = (float*) ((char*)d_ws + partOff);
        int*    histG   = (int*)   ((char*)d_ws + partOff);             // alias: dead
        int*    offG    = (int*)   ((char*)d_ws + partOff + histBytes); // before reduce
        ull*    pairs   = (ull*)   ((char*)d_ws + partOff + partRegion);

        hist_kernel           <<<nTiles, BLOCK1, 0, stream>>>(row, histG, E);
        totals_kernel         <<<NB, 256, 0, stream>>>(histG, totals, nTiles);
        bases_kernel          <<<1, NB, 0, stream>>>(totals, bases);
        offsets_kernel        <<<NB, 256, 0, stream>>>(histG, bases, offG, nTiles);
        scatter_kernel        <<<nTiles, BLOCK1, 0, stream>>>(row, edge_attr, offG, pairs, E);
        reduce_kernel         <<<NB * nSplit, BLOCK2, 0, stream>>>(pairs, totals, bases, partial, nSplit);
        recip_kernel          <<<1024, 256, 0, stream>>>(partial, rnorm16, Np, nSplit);
        gather_scale_f16_kernel<<<2048, 256, 0, stream>>>(col, edge_attr, rnorm16, out, E);
    } else {
        float* rowsum = (float*)d_ws;
        const int workE = (E + 3) >> 2;
        int gE = (workE + 255) / 256;
        if (gE > 2048) gE = 2048;
        zero_ws_kernel        <<<2048, 256, 0, stream>>>(rowsum, Np);
        rowsum_atomic_kernel  <<<gE, 256, 0, stream>>>(row, edge_attr, rowsum, E);
        recip_fallback_kernel <<<2048, 256, 0, stream>>>(rowsum, Np);
        gather_scale_f32_kernel<<<2048, 256, 0, stream>>>(col, edge_attr, rowsum, out, E);
    }
}